// Round 5
// baseline (673.155 us; speedup 1.0000x reference)
//
#include <hip/hip_runtime.h>
#include <hip/hip_bf16.h>
#include <stdint.h>

#define T_DIM 256
#define B_DIM 64
#define DICO  8192
#define EMB   256
#define LAT   256
#define M_DIM (T_DIM*B_DIM)   /* 16384 */

#define BM 128
#define BN 256
#define BK 64
#define KSPLIT 2
#define KCHUNK (DICO/KSPLIT)  /* 4096 */
#define NKS (KCHUNK/BK)       /* 64 */

typedef short  bf16x8 __attribute__((ext_vector_type(8)));
typedef float  f32x4  __attribute__((ext_vector_type(4)));
typedef _Float16 f16x2 __attribute__((ext_vector_type(2)));

__device__ __forceinline__ ushort f2bf(float f) {
  uint32_t u = __float_as_uint(f);
  u += 0x7FFFu + ((u >> 16) & 1u);     // round-to-nearest-even
  return (ushort)(u >> 16);
}

__device__ __forceinline__ void glds16(const void* g, void* l) {
  __builtin_amdgcn_global_load_lds(
      (const __attribute__((address_space(1))) uint32_t*)g,
      (__attribute__((address_space(3))) uint32_t*)l, 16, 0, 0);
}

// ---------------- Kernel 1: Wct[n][k] = sum_e W_emb[k][e] * W_enc[e][n], bf16, n-major
__global__ void wct_kernel(const float* __restrict__ Wemb, const float* __restrict__ Wenc,
                           ushort* __restrict__ wct) {
  const int n  = threadIdx.x;          // 0..255
  const int d0 = blockIdx.x * 32;      // 256 blocks
  __shared__ float we[32 * 256];
  __shared__ float tr[32 * 257];
  #pragma unroll
  for (int r = 0; r < 32; ++r) we[r*256 + n] = Wemb[(size_t)(d0 + r)*EMB + n];
  __syncthreads();
  float acc[32];
  #pragma unroll
  for (int d = 0; d < 32; ++d) acc[d] = 0.f;
  #pragma unroll 4
  for (int e = 0; e < 256; ++e) {
    float wv = Wenc[e*LAT + n];
    #pragma unroll
    for (int d = 0; d < 32; ++d) acc[d] += we[d*256 + e] * wv;   // LDS broadcast
  }
  #pragma unroll
  for (int d = 0; d < 32; ++d) tr[d*257 + n] = acc[d];
  __syncthreads();
  const int nn0 = n >> 2, kc = n & 3;
  #pragma unroll
  for (int p = 0; p < 4; ++p) {
    int nn = p*64 + nn0;
    bf16x8 v;
    #pragma unroll
    for (int j = 0; j < 8; ++j) v[j] = (short)f2bf(tr[(kc*8 + j)*257 + nn]);
    *(bf16x8*)(wct + (size_t)nn*DICO + d0 + kc*8) = v;
  }
}

// ---------------- Kernel 2: xp_part[ksp] = x[:, kchunk] @ Wc[kchunk, :]
// Round-5 change: 512 threads / 8 waves (2 waves/SIMD) to cover waitcnt stalls
// with TLP (round<=4 ran 1 wave/SIMD: every vmcnt/lgkmcnt stall was dead time).
// XOR slot-swizzle involution (round-4, unchanged): LDS rows linear 128 B,
// slot ^= row&7 on BOTH staging source and fragment reads -> conflict-free.
__global__ void __launch_bounds__(512, 1) gemm_kernel(const float* __restrict__ x,
                                                      const ushort* __restrict__ wct,
                                                      float* __restrict__ xp) {
  __shared__ __align__(16) ushort sA[2][BM * BK];   // 16 KB each
  __shared__ __align__(16) ushort sB[2][BN * BK];   // 32 KB each
  const int tid = threadIdx.x;
  const int bid = blockIdx.x;                        // 256 blocks
  const int swzb = (bid & 7) * 32 + (bid >> 3);      // XCD-contiguous (256%8==0)
  const int mt = swzb & 127, ksp = swzb >> 7;        // whole XCD shares ksp (B L2-resident)
  const size_t rowbase = (size_t)mt * BM;
  const int kbase = ksp * KCHUNK;

  const int lane = tid & 63, wid = tid >> 6;
  const int l15 = lane & 15, lc = lane >> 4;
  const int wr = wid >> 2, wc = wid & 3;             // 2x4 wave grid, 64x64 tile each

  // A staging: thread owns row r0 (0..127), 16-float k-chunk c0 (0..3)
  const int r0 = tid >> 2, c0 = tid & 3;
  const float* ag = x + (rowbase + r0) * (size_t)DICO + kbase + c0 * 16;
  const int sx0 = (((2*c0    ) ^ (r0 & 7)) * 16);    // swizzled byte slot, w0
  const int sx1 = (((2*c0 + 1) ^ (r0 & 7)) * 16);    // swizzled byte slot, w1

  // fragment-read swizzled slots (row&7 == l15&7 for all frag rows)
  const int sw0 = (((    lc) ^ (l15 & 7)) * 16);     // k2=0
  const int sw1 = (((4 + lc) ^ (l15 & 7)) * 16);     // k2=1

  const char* wb = (const char*)wct;
  const size_t kb2 = (size_t)kbase * 2;

  // B staging: round r (0..3): row = r*64 + (tid>>3), slot tid&7, linear dest
  const int brow_s = (tid >> 3);
  const int bslot_s = tid & 7;

  f32x4 acc[4][4];
  #pragma unroll
  for (int m = 0; m < 4; ++m)
    #pragma unroll
    for (int n = 0; n < 4; ++n) acc[m][n] = (f32x4){0.f, 0.f, 0.f, 0.f};

  float4 av[4];

  auto loadA = [&](int kofs) {
    #pragma unroll
    for (int q = 0; q < 4; ++q) av[q] = *(const float4*)(ag + kofs + q * 4);
  };
  auto stageB = [&](int buf, int kofs) {
    #pragma unroll
    for (int r = 0; r < 4; ++r) {
      const int row = r * 64 + brow_s;
      const int srcslot = bslot_s ^ (row & 7);       // inverse-swizzled source
      glds16(wb + (size_t)row * (DICO * 2) + kb2 + (size_t)kofs * 2 + srcslot * 16,
             (char*)&sB[buf][0] + r * 8192 + tid * 16);   // linear dest
    }
  };
  auto storeA = [&](int buf) {
    const float4 a0 = av[0], a1 = av[1], a2 = av[2], a3 = av[3];
    bf16x8 w0, w1;
    w0[0]=(short)f2bf(a0.x); w0[1]=(short)f2bf(a0.y); w0[2]=(short)f2bf(a0.z); w0[3]=(short)f2bf(a0.w);
    w0[4]=(short)f2bf(a1.x); w0[5]=(short)f2bf(a1.y); w0[6]=(short)f2bf(a1.z); w0[7]=(short)f2bf(a1.w);
    w1[0]=(short)f2bf(a2.x); w1[1]=(short)f2bf(a2.y); w1[2]=(short)f2bf(a2.z); w1[3]=(short)f2bf(a2.w);
    w1[4]=(short)f2bf(a3.x); w1[5]=(short)f2bf(a3.y); w1[6]=(short)f2bf(a3.z); w1[7]=(short)f2bf(a3.w);
    char* base = (char*)&sA[buf][0] + r0 * 128;
    *(bf16x8*)(base + sx0) = w0;
    *(bf16x8*)(base + sx1) = w1;
  };
  auto compute = [&](int buf) {
    bf16x8 bfr[4][2];
    #pragma unroll
    for (int n = 0; n < 4; ++n) {
      const char* bb = (const char*)&sB[buf][0] + (wc*64 + n*16 + l15) * 128;
      bfr[n][0] = *(const bf16x8*)(bb + sw0);
      bfr[n][1] = *(const bf16x8*)(bb + sw1);
    }
    #pragma unroll
    for (int m = 0; m < 4; ++m) {
      const char* ab = (const char*)&sA[buf][0] + (wr*64 + m*16 + l15) * 128;
      bf16x8 a0 = *(const bf16x8*)(ab + sw0);
      bf16x8 a1 = *(const bf16x8*)(ab + sw1);
      #pragma unroll
      for (int n = 0; n < 4; ++n) {
        acc[m][n] = __builtin_amdgcn_mfma_f32_16x16x32_bf16(a0, bfr[n][0], acc[m][n], 0, 0, 0);
        acc[m][n] = __builtin_amdgcn_mfma_f32_16x16x32_bf16(a1, bfr[n][1], acc[m][n], 0, 0, 0);
      }
    }
  };

  // prologue
  loadA(0);
  stageB(0, 0);
  storeA(0);
  __syncthreads();

  int cur = 0;
  for (int ks = 0; ks < NKS; ++ks) {
    const int kn = (ks + 1) * BK;
    if (ks + 1 < NKS) { loadA(kn); stageB(cur ^ 1, kn); }  // A first in vmcnt FIFO
    compute(cur);
    if (ks + 1 < NKS) storeA(cur ^ 1);                      // waits A loads only
    __syncthreads();                                        // drains glds for next step
    cur ^= 1;
  }

  float* xpo = xp + ((size_t)ksp * M_DIM + rowbase) * LAT;
  #pragma unroll
  for (int m = 0; m < 4; ++m)
    #pragma unroll
    for (int n = 0; n < 4; ++n)
      #pragma unroll
      for (int j = 0; j < 4; ++j)
        xpo[(size_t)(wr*64 + m*16 + lc*4 + j) * LAT + wc*64 + n*16 + l15] = acc[m][n][j];
}

// ---------------- Kernel 3: per-b recurrence h = tanh(xp_t + bc + h@Wh)
// Round-3 structure (reverted from the 16-wave round-4 regression): 4 waves,
// wh[128] in registers, raw s_barrier + lgkmcnt-only wait (vmcnt stays in
// flight for xp prefetch + out stores), double-buffered h.
__global__ void __launch_bounds__(256, 1) rnn_kernel(const float* __restrict__ xp,
                           const float* __restrict__ h0, const float* __restrict__ Wenc,
                           const float* __restrict__ bemb, const float* __restrict__ benc,
                           float* __restrict__ out) {
  const int b = blockIdx.x, l = threadIdx.x;       // 64 blocks x 256 threads
  __shared__ __align__(16) uint32_t hbuf[2][128];  // double-buffered h (f16)
  float bc = benc[l];
  #pragma unroll 8
  for (int e = 0; e < 256; ++e) bc += bemb[e] * Wenc[e*LAT + l];
  f16x2 wh[128];
  #pragma unroll
  for (int j = 0; j < 128; ++j) {
    f16x2 w;
    w[0] = (_Float16)Wenc[(size_t)(EMB + 2*j    )*LAT + l];
    w[1] = (_Float16)Wenc[(size_t)(EMB + 2*j + 1)*LAT + l];
    wh[j] = w;
  }
  ((_Float16*)&hbuf[0][0])[l] = (_Float16)h0[(size_t)b*LAT + l];
  __syncthreads();                                 // one-time full drain (prologue)
  const float* xpb = xp + (size_t)b*LAT + l;
  float*       ob  = out + (size_t)b*LAT + l;
  const size_t ST = (size_t)B_DIM * LAT;           // 16384
  const size_t PO = (size_t)M_DIM * LAT;           // partial offset
  float xa0 = xpb[0],  xa1 = xpb[PO];
  float xb0 = xpb[ST], xb1 = xpb[ST + PO];
  float xc0 = 0.f, xc1 = 0.f;
  for (int t = 0; t < T_DIM; ++t) {
    if (t + 2 < T_DIM) {
      size_t ni = (size_t)(t + 2) * ST;
      xc0 = xpb[ni]; xc1 = xpb[ni + PO];           // stays in flight across barriers
    }
    const uint32_t* hc = &hbuf[t & 1][0];
    float s0=0.f,s1=0.f,s2=0.f,s3=0.f,s4=0.f,s5=0.f,s6=0.f,s7=0.f;
    #pragma unroll
    for (int q = 0; q < 16; ++q) {
      uint4 hv0 = *(const uint4*)(hc + q*8);       // LDS broadcast (uniform addr)
      uint4 hv1 = *(const uint4*)(hc + q*8 + 4);
      s0 = __builtin_amdgcn_fdot2(wh[q*8+0], __builtin_bit_cast(f16x2, hv0.x), s0, false);
      s1 = __builtin_amdgcn_fdot2(wh[q*8+1], __builtin_bit_cast(f16x2, hv0.y), s1, false);
      s2 = __builtin_amdgcn_fdot2(wh[q*8+2], __builtin_bit_cast(f16x2, hv0.z), s2, false);
      s3 = __builtin_amdgcn_fdot2(wh[q*8+3], __builtin_bit_cast(f16x2, hv0.w), s3, false);
      s4 = __builtin_amdgcn_fdot2(wh[q*8+4], __builtin_bit_cast(f16x2, hv1.x), s4, false);
      s5 = __builtin_amdgcn_fdot2(wh[q*8+5], __builtin_bit_cast(f16x2, hv1.y), s5, false);
      s6 = __builtin_amdgcn_fdot2(wh[q*8+6], __builtin_bit_cast(f16x2, hv1.z), s6, false);
      s7 = __builtin_amdgcn_fdot2(wh[q*8+7], __builtin_bit_cast(f16x2, hv1.w), s7, false);
    }
    float pre = (xa0 + xa1) + bc + (((s0+s1)+(s2+s3)) + ((s4+s5)+(s6+s7)));
    float ax = fabsf(pre);
    float e2 = __expf(-2.f * ax);
    float r  = __fdividef(1.f - e2, 1.f + e2);
    float hn = (pre < 0.f) ? -r : r;
    ob[(size_t)t * ST] = hn;                       // fire-and-forget (not drained)
    ((_Float16*)&hbuf[(t + 1) & 1][0])[l] = (_Float16)hn;
    __builtin_amdgcn_sched_barrier(0);
    asm volatile("s_waitcnt lgkmcnt(0)" ::: "memory");   // LDS write visible
    __builtin_amdgcn_s_barrier();                        // vmcnt NOT drained
    __builtin_amdgcn_sched_barrier(0);
    xa0 = xb0; xa1 = xb1; xb0 = xc0; xb1 = xc1;
  }
}

extern "C" void kernel_launch(void* const* d_in, const int* in_sizes, int n_in,
                              void* d_out, int out_size, void* d_ws, size_t ws_size,
                              hipStream_t stream) {
  const float* x    = (const float*)d_in[0];
  const float* h0   = (const float*)d_in[1];
  const float* Wemb = (const float*)d_in[2];
  const float* bemb = (const float*)d_in[3];
  const float* Wenc = (const float*)d_in[4];
  const float* benc = (const float*)d_in[5];
  float* out = (float*)d_out;

  ushort* wct = (ushort*)d_ws;                               // 4 MiB bf16 [256][8192]
  float*  xp  = (float*)((char*)d_ws + ((size_t)4 << 20));   // 2 x 16 MiB fp32 partials

  wct_kernel<<<256, 256, 0, stream>>>(Wemb, Wenc, wct);
  gemm_kernel<<<256, 512, 0, stream>>>(x, wct, xp);
  rnn_kernel<<<64, 256, 0, stream>>>(xp, h0, Wenc, bemb, benc, out);
}

// Round 6
// 660.371 us; speedup vs baseline: 1.0194x; 1.0194x over previous
//
#include <hip/hip_runtime.h>
#include <hip/hip_bf16.h>
#include <stdint.h>

#define T_DIM 256
#define B_DIM 64
#define DICO  8192
#define EMB   256
#define LAT   256
#define M_DIM (T_DIM*B_DIM)   /* 16384 */

#define BM 64
#define BN 256
#define BK 64
#define KSPLIT 2
#define KCHUNK (DICO/KSPLIT)  /* 4096 */
#define NKS (KCHUNK/BK)       /* 64 */

typedef short  bf16x8 __attribute__((ext_vector_type(8)));
typedef float  f32x4  __attribute__((ext_vector_type(4)));
typedef _Float16 f16x2 __attribute__((ext_vector_type(2)));

__device__ __forceinline__ ushort f2bf(float f) {
  uint32_t u = __float_as_uint(f);
  u += 0x7FFFu + ((u >> 16) & 1u);     // round-to-nearest-even
  return (ushort)(u >> 16);
}

__device__ __forceinline__ void glds16(const void* g, void* l) {
  __builtin_amdgcn_global_load_lds(
      (const __attribute__((address_space(1))) uint32_t*)g,
      (__attribute__((address_space(3))) uint32_t*)l, 16, 0, 0);
}

// ---------------- Kernel 1: Wct[n][k] = sum_e W_emb[k][e] * W_enc[e][n], bf16, n-major
__global__ void wct_kernel(const float* __restrict__ Wemb, const float* __restrict__ Wenc,
                           ushort* __restrict__ wct) {
  const int n  = threadIdx.x;          // 0..255
  const int d0 = blockIdx.x * 32;      // 256 blocks
  __shared__ float we[32 * 256];
  __shared__ float tr[32 * 257];
  #pragma unroll
  for (int r = 0; r < 32; ++r) we[r*256 + n] = Wemb[(size_t)(d0 + r)*EMB + n];
  __syncthreads();
  float acc[32];
  #pragma unroll
  for (int d = 0; d < 32; ++d) acc[d] = 0.f;
  #pragma unroll 4
  for (int e = 0; e < 256; ++e) {
    float wv = Wenc[e*LAT + n];
    #pragma unroll
    for (int d = 0; d < 32; ++d) acc[d] += we[d*256 + e] * wv;   // LDS broadcast
  }
  #pragma unroll
  for (int d = 0; d < 32; ++d) tr[d*257 + n] = acc[d];
  __syncthreads();
  const int nn0 = n >> 2, kc = n & 3;
  #pragma unroll
  for (int p = 0; p < 4; ++p) {
    int nn = p*64 + nn0;
    bf16x8 v;
    #pragma unroll
    for (int j = 0; j < 8; ++j) v[j] = (short)f2bf(tr[(kc*8 + j)*257 + nn]);
    *(bf16x8*)(wct + (size_t)nn*DICO + d0 + kc*8) = v;
  }
}

// ---------------- Kernel 2: xp_part[ksp] = x[:, kchunk] @ Wc[kchunk, :]
// Round-6: m97 occupancy clone. BM=64 -> 512 blocks = 2 blocks/CU; 40 KB
// single-buffered LDS. Barrier drains are covered by the co-resident block
// (inter-block TLP) -- intra-block waves can't cover them (lockstep barrier,
// the R2-R5 disease at 96 KB/1 block/CU). XOR slot-swizzle involution kept.
__global__ void __launch_bounds__(256, 2) gemm_kernel(const float* __restrict__ x,
                                                      const ushort* __restrict__ wct,
                                                      float* __restrict__ xp) {
  __shared__ __align__(16) ushort sA[BM * BK];      // 8 KB, single-buffered
  __shared__ __align__(16) ushort sB[BN * BK];      // 32 KB, single-buffered
  const int tid = threadIdx.x;
  const int bid = blockIdx.x;                        // 512 blocks
  const int swzb = (bid & 7) * 64 + (bid >> 3);      // XCD-contiguous (512%8==0)
  const int mt = swzb & 255, ksp = swzb >> 8;        // XCD 0-3: ksp=0, 4-7: ksp=1
  const size_t rowbase = (size_t)mt * BM;
  const int kbase = ksp * KCHUNK;

  const int lane = tid & 63, wid = tid >> 6;         // 4 waves, 1x4 n-grid
  const int l15 = lane & 15, lc = lane >> 4;

  // A staging: thread owns row r0 (0..63), 16-float k-chunk c0 (0..3)
  const int r0 = tid >> 2, c0 = tid & 3;
  const float* ag = x + (rowbase + r0) * (size_t)DICO + kbase + c0 * 16;
  const int sx0 = (((2*c0    ) ^ (r0 & 7)) * 16);    // swizzled byte slot, w0
  const int sx1 = (((2*c0 + 1) ^ (r0 & 7)) * 16);    // swizzled byte slot, w1

  // fragment-read swizzled slots (row&7 == l15&7 for all frag rows)
  const int sw0 = (((    lc) ^ (l15 & 7)) * 16);     // k2=0
  const int sw1 = (((4 + lc) ^ (l15 & 7)) * 16);     // k2=1

  const char* wb = (const char*)wct;
  const size_t kb2 = (size_t)kbase * 2;

  // B staging: round r (0..7): row = r*32 + (tid>>3), slot tid&7, linear dest
  const int brow_s = (tid >> 3);
  const int bslot_s = tid & 7;

  f32x4 acc[4][4];                                   // 64 VGPR
  #pragma unroll
  for (int m = 0; m < 4; ++m)
    #pragma unroll
    for (int n = 0; n < 4; ++n) acc[m][n] = (f32x4){0.f, 0.f, 0.f, 0.f};

  float4 av[4];

  auto loadA = [&](int kofs) {
    #pragma unroll
    for (int q = 0; q < 4; ++q) av[q] = *(const float4*)(ag + kofs + q * 4);
  };
  auto stageB = [&](int kofs) {
    #pragma unroll
    for (int r = 0; r < 8; ++r) {
      const int row = r * 32 + brow_s;
      const int srcslot = bslot_s ^ (row & 7);       // inverse-swizzled source
      glds16(wb + (size_t)row * (DICO * 2) + kb2 + (size_t)kofs * 2 + srcslot * 16,
             (char*)sB + r * 4096 + tid * 16);       // linear dest
    }
  };
  auto storeA = [&]() {
    const float4 a0 = av[0], a1 = av[1], a2 = av[2], a3 = av[3];
    bf16x8 w0, w1;
    w0[0]=(short)f2bf(a0.x); w0[1]=(short)f2bf(a0.y); w0[2]=(short)f2bf(a0.z); w0[3]=(short)f2bf(a0.w);
    w0[4]=(short)f2bf(a1.x); w0[5]=(short)f2bf(a1.y); w0[6]=(short)f2bf(a1.z); w0[7]=(short)f2bf(a1.w);
    w1[0]=(short)f2bf(a2.x); w1[1]=(short)f2bf(a2.y); w1[2]=(short)f2bf(a2.z); w1[3]=(short)f2bf(a2.w);
    w1[4]=(short)f2bf(a3.x); w1[5]=(short)f2bf(a3.y); w1[6]=(short)f2bf(a3.z); w1[7]=(short)f2bf(a3.w);
    char* base = (char*)sA + r0 * 128;
    *(bf16x8*)(base + sx0) = w0;
    *(bf16x8*)(base + sx1) = w1;
  };
  auto compute = [&]() {
    bf16x8 bfr[4][2];
    #pragma unroll
    for (int n = 0; n < 4; ++n) {
      const char* bb = (const char*)sB + (wid*64 + n*16 + l15) * 128;
      bfr[n][0] = *(const bf16x8*)(bb + sw0);
      bfr[n][1] = *(const bf16x8*)(bb + sw1);
    }
    #pragma unroll
    for (int m = 0; m < 4; ++m) {
      const char* ab = (const char*)sA + (m*16 + l15) * 128;
      bf16x8 a0 = *(const bf16x8*)(ab + sw0);
      bf16x8 a1 = *(const bf16x8*)(ab + sw1);
      #pragma unroll
      for (int n = 0; n < 4; ++n) {
        acc[m][n] = __builtin_amdgcn_mfma_f32_16x16x32_bf16(a0, bfr[n][0], acc[m][n], 0, 0, 0);
        acc[m][n] = __builtin_amdgcn_mfma_f32_16x16x32_bf16(a1, bfr[n][1], acc[m][n], 0, 0, 0);
      }
    }
  };

  loadA(0);                                          // prologue
  for (int ks = 0; ks < NKS; ++ks) {
    __syncthreads();                                 // prev compute's LDS reads done
    storeA();                                        // ds_write A(ks) (av from prev iter)
    stageB(ks * BK);                                 // 8 glds B(ks)
    __syncthreads();                                 // drains glds + ds_writes
    if (ks + 1 < NKS) loadA((ks + 1) * BK);          // next A in flight under compute
    compute();
  }

  float* xpo = xp + ((size_t)ksp * M_DIM + rowbase) * LAT;
  #pragma unroll
  for (int m = 0; m < 4; ++m)
    #pragma unroll
    for (int n = 0; n < 4; ++n)
      #pragma unroll
      for (int j = 0; j < 4; ++j)
        xpo[(size_t)(m*16 + lc*4 + j) * LAT + wid*64 + n*16 + l15] = acc[m][n][j];
}

// ---------------- Kernel 3: per-b recurrence h = tanh(xp_t + bc + h@Wh)
// Frozen (R3/R5 structure) for clean attribution: 4 waves, wh[128] in regs,
// raw s_barrier + lgkmcnt-only wait, double-buffered h.
__global__ void __launch_bounds__(256, 1) rnn_kernel(const float* __restrict__ xp,
                           const float* __restrict__ h0, const float* __restrict__ Wenc,
                           const float* __restrict__ bemb, const float* __restrict__ benc,
                           float* __restrict__ out) {
  const int b = blockIdx.x, l = threadIdx.x;       // 64 blocks x 256 threads
  __shared__ __align__(16) uint32_t hbuf[2][128];  // double-buffered h (f16)
  float bc = benc[l];
  #pragma unroll 8
  for (int e = 0; e < 256; ++e) bc += bemb[e] * Wenc[e*LAT + l];
  f16x2 wh[128];
  #pragma unroll
  for (int j = 0; j < 128; ++j) {
    f16x2 w;
    w[0] = (_Float16)Wenc[(size_t)(EMB + 2*j    )*LAT + l];
    w[1] = (_Float16)Wenc[(size_t)(EMB + 2*j + 1)*LAT + l];
    wh[j] = w;
  }
  ((_Float16*)&hbuf[0][0])[l] = (_Float16)h0[(size_t)b*LAT + l];
  __syncthreads();                                 // one-time full drain (prologue)
  const float* xpb = xp + (size_t)b*LAT + l;
  float*       ob  = out + (size_t)b*LAT + l;
  const size_t ST = (size_t)B_DIM * LAT;           // 16384
  const size_t PO = (size_t)M_DIM * LAT;           // partial offset
  float xa0 = xpb[0],  xa1 = xpb[PO];
  float xb0 = xpb[ST], xb1 = xpb[ST + PO];
  float xc0 = 0.f, xc1 = 0.f;
  for (int t = 0; t < T_DIM; ++t) {
    if (t + 2 < T_DIM) {
      size_t ni = (size_t)(t + 2) * ST;
      xc0 = xpb[ni]; xc1 = xpb[ni + PO];           // stays in flight across barriers
    }
    const uint32_t* hc = &hbuf[t & 1][0];
    float s0=0.f,s1=0.f,s2=0.f,s3=0.f,s4=0.f,s5=0.f,s6=0.f,s7=0.f;
    #pragma unroll
    for (int q = 0; q < 16; ++q) {
      uint4 hv0 = *(const uint4*)(hc + q*8);       // LDS broadcast (uniform addr)
      uint4 hv1 = *(const uint4*)(hc + q*8 + 4);
      s0 = __builtin_amdgcn_fdot2(wh[q*8+0], __builtin_bit_cast(f16x2, hv0.x), s0, false);
      s1 = __builtin_amdgcn_fdot2(wh[q*8+1], __builtin_bit_cast(f16x2, hv0.y), s1, false);
      s2 = __builtin_amdgcn_fdot2(wh[q*8+2], __builtin_bit_cast(f16x2, hv0.z), s2, false);
      s3 = __builtin_amdgcn_fdot2(wh[q*8+3], __builtin_bit_cast(f16x2, hv0.w), s3, false);
      s4 = __builtin_amdgcn_fdot2(wh[q*8+4], __builtin_bit_cast(f16x2, hv1.x), s4, false);
      s5 = __builtin_amdgcn_fdot2(wh[q*8+5], __builtin_bit_cast(f16x2, hv1.y), s5, false);
      s6 = __builtin_amdgcn_fdot2(wh[q*8+6], __builtin_bit_cast(f16x2, hv1.z), s6, false);
      s7 = __builtin_amdgcn_fdot2(wh[q*8+7], __builtin_bit_cast(f16x2, hv1.w), s7, false);
    }
    float pre = (xa0 + xa1) + bc + (((s0+s1)+(s2+s3)) + ((s4+s5)+(s6+s7)));
    float ax = fabsf(pre);
    float e2 = __expf(-2.f * ax);
    float r  = __fdividef(1.f - e2, 1.f + e2);
    float hn = (pre < 0.f) ? -r : r;
    ob[(size_t)t * ST] = hn;                       // fire-and-forget (not drained)
    ((_Float16*)&hbuf[(t + 1) & 1][0])[l] = (_Float16)hn;
    __builtin_amdgcn_sched_barrier(0);
    asm volatile("s_waitcnt lgkmcnt(0)" ::: "memory");   // LDS write visible
    __builtin_amdgcn_s_barrier();                        // vmcnt NOT drained
    __builtin_amdgcn_sched_barrier(0);
    xa0 = xb0; xa1 = xb1; xb0 = xc0; xb1 = xc1;
  }
}

extern "C" void kernel_launch(void* const* d_in, const int* in_sizes, int n_in,
                              void* d_out, int out_size, void* d_ws, size_t ws_size,
                              hipStream_t stream) {
  const float* x    = (const float*)d_in[0];
  const float* h0   = (const float*)d_in[1];
  const float* Wemb = (const float*)d_in[2];
  const float* bemb = (const float*)d_in[3];
  const float* Wenc = (const float*)d_in[4];
  const float* benc = (const float*)d_in[5];
  float* out = (float*)d_out;

  ushort* wct = (ushort*)d_ws;                               // 4 MiB bf16 [256][8192]
  float*  xp  = (float*)((char*)d_ws + ((size_t)4 << 20));   // 2 x 16 MiB fp32 partials

  wct_kernel<<<256, 256, 0, stream>>>(Wemb, Wenc, wct);
  gemm_kernel<<<512, 256, 0, stream>>>(x, wct, xp);
  rnn_kernel<<<64, 256, 0, stream>>>(xp, h0, Wenc, bemb, benc, out);
}

// Round 7
// 658.880 us; speedup vs baseline: 1.0217x; 1.0023x over previous
//
#include <hip/hip_runtime.h>
#include <hip/hip_bf16.h>
#include <stdint.h>

#define T_DIM 256
#define B_DIM 64
#define DICO  8192
#define EMB   256
#define LAT   256
#define M_DIM (T_DIM*B_DIM)   /* 16384 */

#define BM 64
#define BN 256
#define BK 64
#define KSPLIT 2
#define KCHUNK (DICO/KSPLIT)  /* 4096 */
#define NKS (KCHUNK/BK)       /* 64 */

typedef short  bf16x8 __attribute__((ext_vector_type(8)));
typedef float  f32x4  __attribute__((ext_vector_type(4)));
typedef _Float16 f16x2 __attribute__((ext_vector_type(2)));

__device__ __forceinline__ ushort f2bf(float f) {
  uint32_t u = __float_as_uint(f);
  u += 0x7FFFu + ((u >> 16) & 1u);     // round-to-nearest-even
  return (ushort)(u >> 16);
}

__device__ __forceinline__ void glds16(const void* g, void* l) {
  __builtin_amdgcn_global_load_lds(
      (const __attribute__((address_space(1))) uint32_t*)g,
      (__attribute__((address_space(3))) uint32_t*)l, 16, 0, 0);
}

// ---------------- Kernel 1: Wct[n][k] = sum_e W_emb[k][e] * W_enc[e][n], bf16, n-major
__global__ void wct_kernel(const float* __restrict__ Wemb, const float* __restrict__ Wenc,
                           ushort* __restrict__ wct) {
  const int n  = threadIdx.x;          // 0..255
  const int d0 = blockIdx.x * 32;      // 256 blocks
  __shared__ float we[32 * 256];
  __shared__ float tr[32 * 257];
  #pragma unroll
  for (int r = 0; r < 32; ++r) we[r*256 + n] = Wemb[(size_t)(d0 + r)*EMB + n];
  __syncthreads();
  float acc[32];
  #pragma unroll
  for (int d = 0; d < 32; ++d) acc[d] = 0.f;
  #pragma unroll 4
  for (int e = 0; e < 256; ++e) {
    float wv = Wenc[e*LAT + n];
    #pragma unroll
    for (int d = 0; d < 32; ++d) acc[d] += we[d*256 + e] * wv;   // LDS broadcast
  }
  #pragma unroll
  for (int d = 0; d < 32; ++d) tr[d*257 + n] = acc[d];
  __syncthreads();
  const int nn0 = n >> 2, kc = n & 3;
  #pragma unroll
  for (int p = 0; p < 4; ++p) {
    int nn = p*64 + nn0;
    bf16x8 v;
    #pragma unroll
    for (int j = 0; j < 8; ++j) v[j] = (short)f2bf(tr[(kc*8 + j)*257 + nn]);
    *(bf16x8*)(wct + (size_t)nn*DICO + d0 + kc*8) = v;
  }
}

// ---------------- Kernel 2: xp_part[ksp] = x[:, kchunk] @ Wc[kchunk, :]
// Round-7: counted-vmcnt pipeline (T3/T4). The R2-R6 plateau was the per-step
// barrier's vmcnt(0) draining the whole A/B stream (x-BW capped at ~one step's
// loads per HBM round-trip). Now: glds B(k+1) [oldest], loadA(k+2) [newest],
// storeA A(k+1), compute(k), then s_waitcnt vmcnt(4) (drains exactly the 8
// B-glds, leaves 4 A-loads in flight) + lgkmcnt(0) + RAW s_barrier. The
// x-stream never drains. Staging/swizzle/fragment code identical to v6.
__global__ void __launch_bounds__(256, 2) gemm_kernel(const float* __restrict__ x,
                                                      const ushort* __restrict__ wct,
                                                      float* __restrict__ xp) {
  __shared__ __align__(16) ushort sA[2][BM * BK];   // 2 x 8 KB
  __shared__ __align__(16) ushort sB[2][BN * BK];   // 2 x 32 KB  (total 80 KB -> 2 blk/CU)
  const int tid = threadIdx.x;
  const int bid = blockIdx.x;                        // 512 blocks
  const int swzb = (bid & 7) * 64 + (bid >> 3);      // XCD-contiguous (512%8==0)
  const int mt = swzb & 255, ksp = swzb >> 8;        // XCD shares ksp (B L2-resident)
  const size_t rowbase = (size_t)mt * BM;
  const int kbase = ksp * KCHUNK;

  const int lane = tid & 63, wid = tid >> 6;         // 4 waves, 1x4 n-grid
  const int l15 = lane & 15, lc = lane >> 4;

  const int r0 = tid >> 2, c0 = tid & 3;
  const float* ag = x + (rowbase + r0) * (size_t)DICO + kbase + c0 * 16;
  const int sx0 = (((2*c0    ) ^ (r0 & 7)) * 16);
  const int sx1 = (((2*c0 + 1) ^ (r0 & 7)) * 16);

  const int sw0 = (((    lc) ^ (l15 & 7)) * 16);
  const int sw1 = (((4 + lc) ^ (l15 & 7)) * 16);

  const char* wb = (const char*)wct;
  const size_t kb2 = (size_t)kbase * 2;

  const int brow_s = (tid >> 3);
  const int bslot_s = tid & 7;

  f32x4 acc[4][4];
  #pragma unroll
  for (int m = 0; m < 4; ++m)
    #pragma unroll
    for (int n = 0; n < 4; ++n) acc[m][n] = (f32x4){0.f, 0.f, 0.f, 0.f};

  float4 avP[4], avQ[4];                             // 2-deep A register banks

  auto stageB = [&](int buf, int kofs) {
    #pragma unroll
    for (int r = 0; r < 8; ++r) {
      const int row = r * 32 + brow_s;
      const int srcslot = bslot_s ^ (row & 7);       // inverse-swizzled source
      glds16(wb + (size_t)row * (DICO * 2) + kb2 + (size_t)kofs * 2 + srcslot * 16,
             (char*)&sB[buf][0] + r * 4096 + tid * 16);   // linear dest
    }
  };
  auto storeA = [&](int buf, const float4* av) {
    const float4 a0 = av[0], a1 = av[1], a2 = av[2], a3 = av[3];
    bf16x8 w0, w1;
    w0[0]=(short)f2bf(a0.x); w0[1]=(short)f2bf(a0.y); w0[2]=(short)f2bf(a0.z); w0[3]=(short)f2bf(a0.w);
    w0[4]=(short)f2bf(a1.x); w0[5]=(short)f2bf(a1.y); w0[6]=(short)f2bf(a1.z); w0[7]=(short)f2bf(a1.w);
    w1[0]=(short)f2bf(a2.x); w1[1]=(short)f2bf(a2.y); w1[2]=(short)f2bf(a2.z); w1[3]=(short)f2bf(a2.w);
    w1[4]=(short)f2bf(a3.x); w1[5]=(short)f2bf(a3.y); w1[6]=(short)f2bf(a3.z); w1[7]=(short)f2bf(a3.w);
    char* base = (char*)&sA[buf][0] + r0 * 128;
    *(bf16x8*)(base + sx0) = w0;
    *(bf16x8*)(base + sx1) = w1;
  };
  auto compute = [&](int buf) {
    bf16x8 bfr[4][2];
    #pragma unroll
    for (int n = 0; n < 4; ++n) {
      const char* bb = (const char*)&sB[buf][0] + (wid*64 + n*16 + l15) * 128;
      bfr[n][0] = *(const bf16x8*)(bb + sw0);
      bfr[n][1] = *(const bf16x8*)(bb + sw1);
    }
    #pragma unroll
    for (int m = 0; m < 4; ++m) {
      const char* ab = (const char*)&sA[buf][0] + (m*16 + l15) * 128;
      bf16x8 a0 = *(const bf16x8*)(ab + sw0);
      bf16x8 a1 = *(const bf16x8*)(ab + sw1);
      #pragma unroll
      for (int n = 0; n < 4; ++n) {
        acc[m][n] = __builtin_amdgcn_mfma_f32_16x16x32_bf16(a0, bfr[n][0], acc[m][n], 0, 0, 0);
        acc[m][n] = __builtin_amdgcn_mfma_f32_16x16x32_bf16(a1, bfr[n][1], acc[m][n], 0, 0, 0);
      }
    }
  };

  // one iteration body. Consumes avC (= A(k+1)) into sA[p^1]; loads A(k+2)
  // into avL; computes on buffers p. Ends with counted-vmcnt + raw barrier.
  auto body = [&](int k, float4* avC, float4* avL) {
    const int p = k & 1;
    const int kB = (k + 1 < NKS ? k + 1 : NKS - 1) * BK;   // clamped (uniform counts)
    const int kA = (k + 2 < NKS ? k + 2 : NKS - 1) * BK;
    stageB(p ^ 1, kB);                               // 8 glds  (oldest in vm FIFO)
    asm volatile("" ::: "memory");                   // pin issue order: B before A
    #pragma unroll
    for (int q = 0; q < 4; ++q) avL[q] = *(const float4*)(ag + kA + q * 4);  // 4 loads (newest)
    storeA(p ^ 1, avC);                              // compiler waits A(k+1) only
    compute(p);
    asm volatile("s_waitcnt vmcnt(4)" ::: "memory"); // my 8 B-glds done; 4 A-loads fly on
    asm volatile("s_waitcnt lgkmcnt(0)" ::: "memory"); // ds_writes visible
    __builtin_amdgcn_s_barrier();                    // raw: no vmcnt(0) drain
    __builtin_amdgcn_sched_barrier(0);
  };

  // prologue: B(0) + A(0) + A(1); full drain once.
  stageB(0, 0);
  #pragma unroll
  for (int q = 0; q < 4; ++q) avP[q] = *(const float4*)(ag + 0   + q * 4);
  #pragma unroll
  for (int q = 0; q < 4; ++q) avQ[q] = *(const float4*)(ag + BK  + q * 4);
  storeA(0, avP);
  __syncthreads();                                   // one-time vmcnt(0)+lgkm(0) drain

  for (int k = 0; k < NKS; k += 2) {                 // unroll-2: static bank roles
    body(k,     avQ, avP);                           // consume A(k+1)=avQ, load A(k+2)->avP
    body(k + 1, avP, avQ);                           // consume A(k+2)=avP, load A(k+3)->avQ
  }

  float* xpo = xp + ((size_t)ksp * M_DIM + rowbase) * LAT;
  #pragma unroll
  for (int m = 0; m < 4; ++m)
    #pragma unroll
    for (int n = 0; n < 4; ++n)
      #pragma unroll
      for (int j = 0; j < 4; ++j)
        xpo[(size_t)(m*16 + lc*4 + j) * LAT + wid*64 + n*16 + l15] = acc[m][n][j];
}

// ---------------- Kernel 3: per-b recurrence h = tanh(xp_t + bc + h@Wh)
// Byte-frozen (R3/R5/R6 structure) for clean attribution.
__global__ void __launch_bounds__(256, 1) rnn_kernel(const float* __restrict__ xp,
                           const float* __restrict__ h0, const float* __restrict__ Wenc,
                           const float* __restrict__ bemb, const float* __restrict__ benc,
                           float* __restrict__ out) {
  const int b = blockIdx.x, l = threadIdx.x;       // 64 blocks x 256 threads
  __shared__ __align__(16) uint32_t hbuf[2][128];  // double-buffered h (f16)
  float bc = benc[l];
  #pragma unroll 8
  for (int e = 0; e < 256; ++e) bc += bemb[e] * Wenc[e*LAT + l];
  f16x2 wh[128];
  #pragma unroll
  for (int j = 0; j < 128; ++j) {
    f16x2 w;
    w[0] = (_Float16)Wenc[(size_t)(EMB + 2*j    )*LAT + l];
    w[1] = (_Float16)Wenc[(size_t)(EMB + 2*j + 1)*LAT + l];
    wh[j] = w;
  }
  ((_Float16*)&hbuf[0][0])[l] = (_Float16)h0[(size_t)b*LAT + l];
  __syncthreads();                                 // one-time full drain (prologue)
  const float* xpb = xp + (size_t)b*LAT + l;
  float*       ob  = out + (size_t)b*LAT + l;
  const size_t ST = (size_t)B_DIM * LAT;           // 16384
  const size_t PO = (size_t)M_DIM * LAT;           // partial offset
  float xa0 = xpb[0],  xa1 = xpb[PO];
  float xb0 = xpb[ST], xb1 = xpb[ST + PO];
  float xc0 = 0.f, xc1 = 0.f;
  for (int t = 0; t < T_DIM; ++t) {
    if (t + 2 < T_DIM) {
      size_t ni = (size_t)(t + 2) * ST;
      xc0 = xpb[ni]; xc1 = xpb[ni + PO];           // stays in flight across barriers
    }
    const uint32_t* hc = &hbuf[t & 1][0];
    float s0=0.f,s1=0.f,s2=0.f,s3=0.f,s4=0.f,s5=0.f,s6=0.f,s7=0.f;
    #pragma unroll
    for (int q = 0; q < 16; ++q) {
      uint4 hv0 = *(const uint4*)(hc + q*8);       // LDS broadcast (uniform addr)
      uint4 hv1 = *(const uint4*)(hc + q*8 + 4);
      s0 = __builtin_amdgcn_fdot2(wh[q*8+0], __builtin_bit_cast(f16x2, hv0.x), s0, false);
      s1 = __builtin_amdgcn_fdot2(wh[q*8+1], __builtin_bit_cast(f16x2, hv0.y), s1, false);
      s2 = __builtin_amdgcn_fdot2(wh[q*8+2], __builtin_bit_cast(f16x2, hv0.z), s2, false);
      s3 = __builtin_amdgcn_fdot2(wh[q*8+3], __builtin_bit_cast(f16x2, hv0.w), s3, false);
      s4 = __builtin_amdgcn_fdot2(wh[q*8+4], __builtin_bit_cast(f16x2, hv1.x), s4, false);
      s5 = __builtin_amdgcn_fdot2(wh[q*8+5], __builtin_bit_cast(f16x2, hv1.y), s5, false);
      s6 = __builtin_amdgcn_fdot2(wh[q*8+6], __builtin_bit_cast(f16x2, hv1.z), s6, false);
      s7 = __builtin_amdgcn_fdot2(wh[q*8+7], __builtin_bit_cast(f16x2, hv1.w), s7, false);
    }
    float pre = (xa0 + xa1) + bc + (((s0+s1)+(s2+s3)) + ((s4+s5)+(s6+s7)));
    float ax = fabsf(pre);
    float e2 = __expf(-2.f * ax);
    float r  = __fdividef(1.f - e2, 1.f + e2);
    float hn = (pre < 0.f) ? -r : r;
    ob[(size_t)t * ST] = hn;                       // fire-and-forget (not drained)
    ((_Float16*)&hbuf[(t + 1) & 1][0])[l] = (_Float16)hn;
    __builtin_amdgcn_sched_barrier(0);
    asm volatile("s_waitcnt lgkmcnt(0)" ::: "memory");   // LDS write visible
    __builtin_amdgcn_s_barrier();                        // vmcnt NOT drained
    __builtin_amdgcn_sched_barrier(0);
    xa0 = xb0; xa1 = xb1; xb0 = xc0; xb1 = xc1;
  }
}

extern "C" void kernel_launch(void* const* d_in, const int* in_sizes, int n_in,
                              void* d_out, int out_size, void* d_ws, size_t ws_size,
                              hipStream_t stream) {
  const float* x    = (const float*)d_in[0];
  const float* h0   = (const float*)d_in[1];
  const float* Wemb = (const float*)d_in[2];
  const float* bemb = (const float*)d_in[3];
  const float* Wenc = (const float*)d_in[4];
  const float* benc = (const float*)d_in[5];
  float* out = (float*)d_out;

  ushort* wct = (ushort*)d_ws;                               // 4 MiB bf16 [256][8192]
  float*  xp  = (float*)((char*)d_ws + ((size_t)4 << 20));   // 2 x 16 MiB fp32 partials

  wct_kernel<<<256, 256, 0, stream>>>(Wemb, Wenc, wct);
  gemm_kernel<<<512, 256, 0, stream>>>(x, wct, xp);
  rnn_kernel<<<64, 256, 0, stream>>>(xp, h0, Wenc, bemb, benc, out);
}